// Round 1
// baseline (372.292 us; speedup 1.0000x reference)
//
#include <hip/hip_runtime.h>
#include <stdint.h>

// out[b,m,f] = sum_n x[b,n,f] * (support[n,m]*kernel[n,m]) + bias[f]
// support is a k-hop ring mask -> ~7 nonzeros per column. Strategy:
//   1) build_csc_kernel: compact W columns into (cnt, idx, val) in d_ws
//   2) spmm_kernel: 1 block per (b,m); thread t owns float4 f-slice; ~7-tap
//      gather, coalesced 16B/lane. XCD swizzle keeps one batch's m-blocks on
//      one XCD so the 7x row re-reads are L2-local.

__global__ void build_csc_kernel(const float* __restrict__ support,
                                 const float* __restrict__ kern,
                                 int* __restrict__ cnt,
                                 int* __restrict__ idx,
                                 float* __restrict__ val,
                                 int n) {
    const int m = blockIdx.x;      // one column per block
    const int lane = threadIdx.x;  // 64 threads = one wave
    int base = 0;
    for (int n0 = 0; n0 < n; n0 += 64) {
        const int row = n0 + lane;
        float w = 0.0f;
        if (row < n) w = support[(size_t)row * n + m] * kern[(size_t)row * n + m];
        const unsigned long long mask = __ballot(w != 0.0f);
        const int pos = base + (int)__popcll(mask & ((1ull << lane) - 1ull));
        if (w != 0.0f) {
            idx[(size_t)m * n + pos] = row;
            val[(size_t)m * n + pos] = w;
        }
        base += (int)__popcll(mask);
    }
    if (lane == 0) cnt[m] = base;
}

__global__ __launch_bounds__(256) void spmm_kernel(
    const float4* __restrict__ x, const float* __restrict__ bias,
    const int* __restrict__ cnt, const int* __restrict__ idx,
    const float* __restrict__ val, float4* __restrict__ out,
    int n, int f4, int swizzle) {
    const int blk = blockIdx.x;
    int b, m;
    if (swizzle) {
        // all m-blocks of one batch b land on one XCD, consecutively
        const int xcd = blk & 7;
        const int ii = blk >> 3;
        b = xcd + 8 * (ii / n);
        m = ii % n;
    } else {
        b = blk / n;
        m = blk % n;
    }
    const int c = cnt[m];
    const int* __restrict__ ip = idx + (size_t)m * n;
    const float* __restrict__ vp = val + (size_t)m * n;
    const float4* __restrict__ b4 = (const float4*)bias;
    const size_t xbase = (size_t)b * n * f4;
    const size_t obase = ((size_t)b * n + m) * f4;
    for (int t = threadIdx.x; t < f4; t += 256) {
        float4 acc = b4[t];
        for (int j = 0; j < c; ++j) {
            const int nn = ip[j];
            const float w = vp[j];
            const float4 v = x[xbase + (size_t)nn * f4 + t];
            acc.x = fmaf(w, v.x, acc.x);
            acc.y = fmaf(w, v.y, acc.y);
            acc.z = fmaf(w, v.z, acc.z);
            acc.w = fmaf(w, v.w, acc.w);
        }
        out[obase + t] = acc;
    }
}

// Correctness fallback if d_ws is too small for the CSC arrays (unlikely).
__global__ __launch_bounds__(256) void dense_fallback_kernel(
    const float4* __restrict__ x, const float* __restrict__ support,
    const float* __restrict__ kern, const float* __restrict__ bias,
    float4* __restrict__ out, int n, int f4) {
    const int blk = blockIdx.x;
    const int b = blk / n;
    const int m = blk % n;
    const float4* __restrict__ b4 = (const float4*)bias;
    const size_t xbase = (size_t)b * n * f4;
    const size_t obase = ((size_t)b * n + m) * f4;
    for (int t = threadIdx.x; t < f4; t += 256) {
        float4 acc = b4[t];
        for (int nn = 0; nn < n; ++nn) {
            const float w = support[(size_t)nn * n + m] * kern[(size_t)nn * n + m];
            if (w != 0.0f) {
                const float4 v = x[xbase + (size_t)nn * f4 + t];
                acc.x = fmaf(w, v.x, acc.x);
                acc.y = fmaf(w, v.y, acc.y);
                acc.z = fmaf(w, v.z, acc.z);
                acc.w = fmaf(w, v.w, acc.w);
            }
        }
        out[obase + t] = acc;
    }
}

extern "C" void kernel_launch(void* const* d_in, const int* in_sizes, int n_in,
                              void* d_out, int out_size, void* d_ws, size_t ws_size,
                              hipStream_t stream) {
    const float* x       = (const float*)d_in[0];
    const float* support = (const float*)d_in[1];
    const float* kern    = (const float*)d_in[2];
    const float* bias    = (const float*)d_in[3];
    float* out = (float*)d_out;

    // n from support (n*n elements); f from bias; batch from x.
    const int nsq = in_sizes[1];
    int n = 1;
    while (n * n < nsq) ++n;          // n = 199
    const int f = in_sizes[3];        // 1024
    const int f4 = f / 4;             // 256
    const int batch = in_sizes[0] / (n * f);  // 256

    const size_t need = ((size_t)n + 2u * (size_t)n * (size_t)n) * 4u;
    if (ws_size >= need && (f % 4) == 0) {
        int* cnt = (int*)d_ws;
        int* idx = cnt + n;
        float* val = (float*)(idx + (size_t)n * n);
        build_csc_kernel<<<n, 64, 0, stream>>>(support, kern, cnt, idx, val, n);
        const int swz = (batch % 8 == 0) ? 1 : 0;
        spmm_kernel<<<batch * n, 256, 0, stream>>>(
            (const float4*)x, bias, cnt, idx, val, (float4*)out, n, f4, swz);
    } else {
        dense_fallback_kernel<<<batch * n, 256, 0, stream>>>(
            (const float4*)x, support, kern, bias, (float4*)out, n, f / 4);
    }
}